// Round 3
// baseline (962.094 us; speedup 1.0000x reference)
//
#include <hip/hip_runtime.h>

typedef unsigned short u16;
typedef __bf16 bf16x8 __attribute__((ext_vector_type(8)));
typedef float f32x4 __attribute__((ext_vector_type(4)));

typedef const __attribute__((address_space(1))) void gv_t;
typedef __attribute__((address_space(3))) void lv_t;

__device__ __forceinline__ float b2f(u16 u) {
    union { unsigned int i; float f; } v; v.i = ((unsigned int)u) << 16; return v.f;
}
__device__ __forceinline__ u16 f2b(float f) {
    union { unsigned int i; float f; } v; v.f = f;
    unsigned int b = v.i;
    return (u16)((b + 0x7FFFu + ((b >> 16) & 1u)) >> 16);
}

// Hamilton product tables: out component p, input component q -> weight index / sign
__constant__ int   c_qidx[16] = {0,1,2,3, 1,0,3,2, 2,3,0,1, 3,2,1,0};
__constant__ float c_qsgn[16] = {1,-1,-1,-1, 1,1,1,-1, 1,-1,1,1, 1,1,-1,1};

// ---------------------------------------------------------------- weights ---
__global__ void build_weights(const float* __restrict__ wqkv, const float* __restrict__ wproj,
                              const float* __restrict__ wf1, const float* __restrict__ wf2,
                              const float* __restrict__ wpe,
                              u16* __restrict__ Wq, u16* __restrict__ Wp, u16* __restrict__ W1,
                              u16* __restrict__ W2, float* __restrict__ Wpe_eff)
{
    long i = (long)blockIdx.x * 256 + threadIdx.x;
    if (i < 3145728L) {  // qkv: M=3072 K=1024
        int m = (int)(i >> 10), k = (int)(i & 1023);
        int o = m >> 2, p = m & 3, c = k >> 2, q = k & 3, pq = (p << 2) | q;
        Wq[i] = f2b(c_qsgn[pq] * wqkv[c_qidx[pq] * 196608 + o * 256 + c]);
        return;
    }
    i -= 3145728L;
    if (i < 1048576L) {  // proj: 1024x1024
        int m = (int)(i >> 10), k = (int)(i & 1023);
        int o = m >> 2, p = m & 3, c = k >> 2, q = k & 3, pq = (p << 2) | q;
        Wp[i] = f2b(c_qsgn[pq] * wproj[c_qidx[pq] * 65536 + o * 256 + c]);
        return;
    }
    i -= 1048576L;
    if (i < 2097152L) {  // f1: 2048x1024
        int m = (int)(i >> 10), k = (int)(i & 1023);
        int o = m >> 2, p = m & 3, c = k >> 2, q = k & 3, pq = (p << 2) | q;
        W1[i] = f2b(c_qsgn[pq] * wf1[c_qidx[pq] * 131072 + o * 256 + c]);
        return;
    }
    i -= 2097152L;
    if (i < 2097152L) {  // f2: 1024x2048
        int m = (int)(i >> 11), k = (int)(i & 2047);
        int o = m >> 2, p = m & 3, c = k >> 2, q = k & 3, pq = (p << 2) | q;
        W2[i] = f2b(c_qsgn[pq] * wf2[c_qidx[pq] * 131072 + o * 512 + c]);
        return;
    }
    i -= 2097152L;
    if (i < 147456L) {   // pe: [g][tap][fi][of], fp32
        int g = (int)(i / 2304), r = (int)(i % 2304);
        int tap = r >> 8, r2 = r & 255;
        int fi = r2 >> 4, of = r2 & 15;
        int ol = of >> 2, p = of & 3, ci = fi >> 2, q = fi & 3, pq = (p << 2) | q;
        Wpe_eff[i] = c_qsgn[pq] * wpe[c_qidx[pq] * 9216 + (g * 4 + ol) * 36 + ci * 9 + tap];
    }
}

__global__ void zero_f(float* __restrict__ a)
{
    a[blockIdx.x * 256 + threadIdx.x] = 0.f;
}

// ------------------------------------------------- cast + transpose of x ---
// x fp32 [b][1024][4096] -> Xt bf16 [b][4096][1024]
__global__ __launch_bounds__(256) void cast_tr(const float* __restrict__ x, u16* __restrict__ Xt)
{
    int b = blockIdx.z, mt = blockIdx.y * 64, nt = blockIdx.x * 64;
    __shared__ u16 tl[64][66];
    int t = threadIdx.x, sub = t >> 4, c4 = (t & 15) * 4;
#pragma unroll
    for (int rr = 0; rr < 4; rr++) {
        int row = rr * 16 + sub;
        float4 v = *(const float4*)(x + ((long)b * 1024 + mt + row) * 4096 + nt + c4);
        uint2 pk;
        pk.x = (unsigned int)f2b(v.x) | ((unsigned int)f2b(v.y) << 16);
        pk.y = (unsigned int)f2b(v.z) | ((unsigned int)f2b(v.w) << 16);
        *(uint2*)(&tl[row][c4]) = pk;
    }
    __syncthreads();
#pragma unroll
    for (int rr = 0; rr < 4; rr++) {
        int row = rr * 16 + sub;
        uint2 o;
        o.x = (unsigned int)tl[c4][row] | ((unsigned int)tl[c4 + 1][row] << 16);
        o.y = (unsigned int)tl[c4 + 2][row] | ((unsigned int)tl[c4 + 3][row] << 16);
        *(uint2*)(Xt + ((long)b * 4096 + nt + row) * 1024 + mt + c4) = o;
    }
}

// ------------------------------------------------------------------ GEMM ---
// C = A[M][K] x Bt[b][N][K]^T.  Fragment-major LDS: each MFMA fragment is a
// contiguous 1KB LDS block (conflict-free b128 reads).  TROUT=true writes
// C[b][N][M] (pixel-major) via LDS epilogue transpose.
__device__ __forceinline__ void async_copy16(const u16* g, u16* l) {
    __builtin_amdgcn_global_load_lds((gv_t*)g, (lv_t*)l, 16, 0, 0);
}

template<bool TROUT>
__global__ __launch_bounds__(256) void gemm_bt(
    const u16* __restrict__ A, const u16* __restrict__ Bt, u16* __restrict__ C,
    int M, int N, int K, long strideB, long strideC)
{
    __shared__ __align__(16) u16 smem[TROUT ? 17408 : 8192];
    u16* As = smem;
    u16* Bs = smem + 4096;
    const int t = threadIdx.x;
    const int b = blockIdx.z;
    const u16* Bb = Bt + (long)b * strideB;
    const int m0 = blockIdx.y * 128, n0 = blockIdx.x * 128;
    const int l = t & 63, w = t >> 6;
    const int wm = (w >> 1) * 64, wn = (w & 1) * 64;
    const int quad = l >> 4, r16 = l & 15;

    // staging: thread t fetches frag-position l of 16-row group; group = wave
    const int srow = (w << 4) + r16;        // 0..63
    const int sk8 = ((l >> 4) << 3);        // 0,8,16,24

    // fragment read bases (contiguous 64x16B per fragment)
    const u16* a_rd = As + (w >> 1) * 2048 + l * 8;   // + i*512
    const u16* b_rd = Bs + (w & 1) * 2048 + l * 8;    // + j*512

    f32x4 acc[4][4];
#pragma unroll
    for (int i = 0; i < 4; i++)
#pragma unroll
        for (int j = 0; j < 4; j++) acc[i][j] = (f32x4){0.f, 0.f, 0.f, 0.f};

    const u16* gA0 = A + (long)(m0 + srow) * K + sk8;
    const u16* gA1 = A + (long)(m0 + srow + 64) * K + sk8;
    const u16* gB0 = Bb + (long)(n0 + srow) * K + sk8;
    const u16* gB1 = Bb + (long)(n0 + srow + 64) * K + sk8;
    u16* lA0 = As + t * 8; u16* lA1 = As + (t + 256) * 8;
    u16* lB0 = Bs + t * 8; u16* lB1 = Bs + (t + 256) * 8;

    for (int kt = 0; kt < K; kt += 32) {
        async_copy16(gA0 + kt, lA0);
        async_copy16(gA1 + kt, lA1);
        async_copy16(gB0 + kt, lB0);
        async_copy16(gB1 + kt, lB1);
        __syncthreads();
        bf16x8 bfr[4];
#pragma unroll
        for (int j = 0; j < 4; j++) bfr[j] = *(const bf16x8*)(b_rd + j * 512);
#pragma unroll
        for (int i = 0; i < 4; i++) {
            bf16x8 af = *(const bf16x8*)(a_rd + i * 512);
#pragma unroll
            for (int j = 0; j < 4; j++)
                acc[i][j] = __builtin_amdgcn_mfma_f32_16x16x32_bf16(af, bfr[j], acc[i][j], 0, 0, 0);
        }
        __syncthreads();
    }

    if (!TROUT) {
        u16* Cb = C + (long)b * strideC;
#pragma unroll
        for (int i = 0; i < 4; i++)
#pragma unroll
            for (int j = 0; j < 4; j++) {
                int mm = m0 + wm + i * 16 + quad * 4;
                int nn = n0 + wn + j * 16 + r16;
#pragma unroll
                for (int r = 0; r < 4; r++)
                    Cb[(long)(mm + r) * N + nn] = f2b(acc[i][j][r]);
            }
    } else {
        u16* Ct = smem;
#pragma unroll
        for (int i = 0; i < 4; i++)
#pragma unroll
            for (int j = 0; j < 4; j++) {
                int mm = wm + i * 16 + quad * 4;
                int nn = wn + j * 16 + r16;
                ushort4 pk;
                pk.x = f2b(acc[i][j][0]); pk.y = f2b(acc[i][j][1]);
                pk.z = f2b(acc[i][j][2]); pk.w = f2b(acc[i][j][3]);
                *(ushort4*)(Ct + nn * 136 + mm) = pk;
            }
        __syncthreads();
        u16* Cb = C + (long)b * strideC;
        for (int rr = 0; rr < 128; rr += 16) {
            int n = rr + (t >> 4);
            int m8 = (t & 15) * 8;
            uint4 v = *(const uint4*)(Ct + n * 136 + m8);
            *(uint4*)(Cb + (long)(n0 + n) * M + m0 + m8) = v;
        }
    }
}

// ------------------------------------------------------------- attention ---
// Phase 1: partial S over 1024-pixel chunks, 512 blocks, atomicAdd reduce.
__global__ __launch_bounds__(256) void attn_s(const u16* __restrict__ QKV, float* __restrict__ S)
{
    const int chunk = blockIdx.x, bhp = blockIdx.y;
    const int bi = bhp >> 5, h = (bhp >> 2) & 7, p = bhp & 3;
    const long rs = 16384;
    const u16* base = QKV + (long)bi * (3072L * 4096) + (long)(h * 384 + p) * 4096;
    const int t = threadIdx.x, l = t & 63, w = t >> 6;
    const int quad = l >> 4, r16 = l & 15;
    __shared__ float Sred[4][32][32];

    f32x4 acc[2][2];
#pragma unroll
    for (int i = 0; i < 2; i++)
#pragma unroll
        for (int j = 0; j < 2; j++) acc[i][j] = (f32x4){0.f, 0.f, 0.f, 0.f};

    const int nb = chunk * 1024 + w * 256 + quad * 8;
    for (int kk = 0; kk < 256; kk += 32) {
        long off = nb + kk;
        bf16x8 q0 = *(const bf16x8*)(base + (long)r16 * rs + off);
        bf16x8 q1 = *(const bf16x8*)(base + (long)(16 + r16) * rs + off);
        bf16x8 k0 = *(const bf16x8*)(base + (long)(32 + r16) * rs + off);
        bf16x8 k1 = *(const bf16x8*)(base + (long)(48 + r16) * rs + off);
        acc[0][0] = __builtin_amdgcn_mfma_f32_16x16x32_bf16(q0, k0, acc[0][0], 0, 0, 0);
        acc[0][1] = __builtin_amdgcn_mfma_f32_16x16x32_bf16(q0, k1, acc[0][1], 0, 0, 0);
        acc[1][0] = __builtin_amdgcn_mfma_f32_16x16x32_bf16(q1, k0, acc[1][0], 0, 0, 0);
        acc[1][1] = __builtin_amdgcn_mfma_f32_16x16x32_bf16(q1, k1, acc[1][1], 0, 0, 0);
    }
#pragma unroll
    for (int i = 0; i < 2; i++)
#pragma unroll
        for (int j = 0; j < 2; j++)
#pragma unroll
            for (int r = 0; r < 4; r++)
                Sred[w][i * 16 + quad * 4 + r][j * 16 + r16] = acc[i][j][r];
    __syncthreads();
    for (int e = t; e < 1024; e += 256) {
        int c = e >> 5, d = e & 31;
        float v = Sred[0][c][d] + Sred[1][c][d] + Sred[2][c][d] + Sred[3][c][d];
        atomicAdd(&S[(long)bhp * 1024 + e], v);
    }
}

// Phase 2: scale + softmax rows, in place.  128 tiny blocks.
__global__ __launch_bounds__(64) void attn_soft(float* __restrict__ S)
{
    const int bhp = blockIdx.x, t = threadIdx.x;
    if (t >= 32) return;
    float* row = S + (long)bhp * 1024 + t * 32;
    float r[32];
    float mx = -1e30f;
#pragma unroll
    for (int d = 0; d < 32; d++) { r[d] = row[d] * 0.17677669529663687f; mx = fmaxf(mx, r[d]); }
    float sum = 0.f;
#pragma unroll
    for (int d = 0; d < 32; d++) { r[d] = __expf(r[d] - mx); sum += r[d]; }
    float inv = 1.f / sum;
#pragma unroll
    for (int d = 0; d < 32; d++) row[d] = r[d] * inv;
}

// Phase 3: O = P V.  1024 blocks, 512 pixels each, 2 px/thread.
__global__ __launch_bounds__(256) void attn_pv(const u16* __restrict__ QKV, const float* __restrict__ S,
                                               u16* __restrict__ O)
{
    const int ns = blockIdx.x * 512, bhp = blockIdx.y;
    const int bi = bhp >> 5, h = (bhp >> 2) & 7, p = bhp & 3;
    const long rs = 16384;
    const u16* base = QKV + (long)bi * (3072L * 4096) + (long)(h * 384 + p) * 4096;
    const int t = threadIdx.x;
    __shared__ float Pl[1024];
    for (int e = t; e < 1024; e += 256) Pl[e] = S[(long)bhp * 1024 + e];
    __syncthreads();

    float v[32][2];
#pragma unroll
    for (int d = 0; d < 32; d++) {
        unsigned int u = *(const unsigned int*)(base + (long)(64 + d) * rs + ns + 2 * t);
        v[d][0] = b2f((u16)u); v[d][1] = b2f((u16)(u >> 16));
    }
    u16* Ob = O + (long)bi * (1024L * 4096) + (long)(h * 128 + p) * 4096;
    for (int c = 0; c < 32; c++) {
        float s0 = 0.f, s1 = 0.f;
        const float4* prow = (const float4*)(&Pl[c * 32]);
#pragma unroll
        for (int dq = 0; dq < 8; dq++) {
            float4 pv = prow[dq];
            s0 = fmaf(pv.x, v[4*dq+0][0], s0); s1 = fmaf(pv.x, v[4*dq+0][1], s1);
            s0 = fmaf(pv.y, v[4*dq+1][0], s0); s1 = fmaf(pv.y, v[4*dq+1][1], s1);
            s0 = fmaf(pv.z, v[4*dq+2][0], s0); s1 = fmaf(pv.z, v[4*dq+2][1], s1);
            s0 = fmaf(pv.w, v[4*dq+3][0], s0); s1 = fmaf(pv.w, v[4*dq+3][1], s1);
        }
        *(unsigned int*)(Ob + (long)c * 16384 + ns + 2 * t) =
            (unsigned int)f2b(s0) | ((unsigned int)f2b(s1) << 16);
    }
}

// ------------------------------------------------------ pe conv + residual ---
// O2t[b][n][feat] = O + qconv_pe(O)
__global__ __launch_bounds__(256) void pe_kernel(const u16* __restrict__ Oin,
                                                 const float* __restrict__ Wpe,
                                                 u16* __restrict__ O2t)
{
    const int tile = blockIdx.x, g = blockIdx.y, bi = blockIdx.z;
    const int y0 = (tile >> 2) * 16, x0 = (tile & 3) * 16;
    __shared__ float tin[16][324];  // 16 feats x 18x18 halo tile
    const int t = threadIdx.x;
    const u16* Ob = Oin + (long)bi * (1024L * 4096) + (long)(g * 16) * 4096;
    for (int e = t; e < 16 * 324; e += 256) {
        int f = e / 324, rem = e % 324;
        int yy = rem / 18 - 1 + y0, xx = rem % 18 - 1 + x0;
        float v = 0.f;
        if (yy >= 0 && yy < 64 && xx >= 0 && xx < 64)
            v = b2f(Ob[(long)f * 4096 + yy * 64 + xx]);
        tin[f][rem] = v;
    }
    __syncthreads();
    const int y = t >> 4, x = t & 15;
    float acc[16];
#pragma unroll
    for (int of = 0; of < 16; of++) acc[of] = tin[of][(y + 1) * 18 + (x + 1)];  // residual
    const float* Wg = Wpe + g * 2304;
    for (int dy = 0; dy < 3; dy++)
        for (int dx = 0; dx < 3; dx++) {
            int off = (y + dy) * 18 + (x + dx);
            int tap = dy * 3 + dx;
            for (int fi = 0; fi < 16; fi++) {
                float v = tin[fi][off];
                const float* wp = Wg + (tap * 16 + fi) * 16;
#pragma unroll
                for (int of = 0; of < 16; of++) acc[of] = fmaf(wp[of], v, acc[of]);
            }
        }
    long n = (long)(y0 + y) * 64 + (x0 + x);
    unsigned int* op = (unsigned int*)(O2t + ((long)bi * 4096 + n) * 1024 + g * 16);
#pragma unroll
    for (int u = 0; u < 8; u++)
        op[u] = (unsigned int)f2b(acc[2 * u]) | ((unsigned int)f2b(acc[2 * u + 1]) << 16);
}

// ----------------------------------------- BN stats, feature-major layout ---
__global__ __launch_bounds__(256) void bn_stats(const u16* __restrict__ X, float* __restrict__ stats, int M)
{
    const int m = blockIdx.x, t = threadIdx.x;
    float s = 0.f, ss = 0.f;
    for (int b = 0; b < 4; b++) {
        const u16* rowp = X + ((long)b * M + m) * 4096;
        for (int pass = 0; pass < 2; pass++) {
            uint4 uv = *(const uint4*)(rowp + pass * 2048 + t * 8);
            unsigned int wsa[4] = {uv.x, uv.y, uv.z, uv.w};
#pragma unroll
            for (int u = 0; u < 4; u++) {
                float v0 = b2f((u16)wsa[u]), v1 = b2f((u16)(wsa[u] >> 16));
                s += v0 + v1; ss += v0 * v0 + v1 * v1;
            }
        }
    }
    __shared__ float rs[4], rss[4];
    for (int o = 32; o > 0; o >>= 1) { s += __shfl_down(s, o); ss += __shfl_down(ss, o); }
    if ((t & 63) == 0) { rs[t >> 6] = s; rss[t >> 6] = ss; }
    __syncthreads();
    if (t == 0) {
        float S = rs[0] + rs[1] + rs[2] + rs[3];
        float SS = rss[0] + rss[1] + rss[2] + rss[3];
        float mean = S * (1.f / 16384.f);
        float var = SS * (1.f / 16384.f) - mean * mean;
        stats[2 * m] = mean;
        stats[2 * m + 1] = rsqrtf(var + 1e-5f);
    }
}

// ------------------------------------------- X1t = cast_tr(x + BN(P)) bf16 ---
__global__ __launch_bounds__(256) void bn_add_tr(const float* __restrict__ x, const u16* __restrict__ P,
    const float* __restrict__ stats, const float* __restrict__ gamma, const float* __restrict__ beta,
    u16* __restrict__ X1t)
{
    int b = blockIdx.z, mt = blockIdx.y * 64, nt = blockIdx.x * 64;
    __shared__ u16 tl[64][66];
    int t = threadIdx.x, sub = t >> 4, c4 = (t & 15) * 4;
#pragma unroll
    for (int rr = 0; rr < 4; rr++) {
        int row = rr * 16 + sub, m = mt + row;
        float gm = gamma[m] * stats[2 * m + 1];
        float bs = beta[m] - gm * stats[2 * m];
        long gi = ((long)b * 1024 + m) * 4096 + nt + c4;
        float4 xv = *(const float4*)(x + gi);
        uint2 pv = *(const uint2*)(P + gi);
        uint2 pk;
        pk.x = (unsigned int)f2b(xv.x + fmaf(gm, b2f((u16)pv.x), bs)) |
               ((unsigned int)f2b(xv.y + fmaf(gm, b2f((u16)(pv.x >> 16)), bs)) << 16);
        pk.y = (unsigned int)f2b(xv.z + fmaf(gm, b2f((u16)pv.y), bs)) |
               ((unsigned int)f2b(xv.w + fmaf(gm, b2f((u16)(pv.y >> 16)), bs)) << 16);
        *(uint2*)(&tl[row][c4]) = pk;
    }
    __syncthreads();
#pragma unroll
    for (int rr = 0; rr < 4; rr++) {
        int row = rr * 16 + sub;
        uint2 o;
        o.x = (unsigned int)tl[c4][row] | ((unsigned int)tl[c4 + 1][row] << 16);
        o.y = (unsigned int)tl[c4 + 2][row] | ((unsigned int)tl[c4 + 3][row] << 16);
        *(uint2*)(X1t + ((long)b * 4096 + nt + row) * 1024 + mt + c4) = o;
    }
}

// ----------------------------- BN stats over pixel-major [16384][2048] bf16 ---
__global__ __launch_bounds__(256) void bn_stats_col(const u16* __restrict__ Xp, float* __restrict__ accum)
{
    const int t = threadIdx.x;
    const int f0 = t * 8;
    float s[8], ss[8];
#pragma unroll
    for (int u = 0; u < 8; u++) { s[u] = 0.f; ss[u] = 0.f; }
    const u16* base = Xp + (long)blockIdx.x * 128 * 2048;
    for (int r = 0; r < 128; r++) {
        uint4 uv = *(const uint4*)(base + (long)r * 2048 + f0);
        unsigned int wsa[4] = {uv.x, uv.y, uv.z, uv.w};
#pragma unroll
        for (int u = 0; u < 4; u++) {
            float v0 = b2f((u16)wsa[u]), v1 = b2f((u16)(wsa[u] >> 16));
            s[2*u] += v0;   ss[2*u]   += v0 * v0;
            s[2*u+1] += v1; ss[2*u+1] += v1 * v1;
        }
    }
#pragma unroll
    for (int u = 0; u < 8; u++) {
        atomicAdd(&accum[f0 + u], s[u]);
        atomicAdd(&accum[2048 + f0 + u], ss[u]);
    }
}

// --------------------------------- in-place relu(BN(.)) on pixel-major F1 ---
__global__ __launch_bounds__(256) void bn_relu_ip(u16* __restrict__ Xp, const float* __restrict__ accum,
    const float* __restrict__ gamma, const float* __restrict__ beta)
{
    long i = ((long)blockIdx.x * 256 + threadIdx.x) * 8;
    int f = (int)(i & 2047);
    uint4 uv = *(const uint4*)(Xp + i);
    unsigned int wsa[4] = {uv.x, uv.y, uv.z, uv.w};
    unsigned int ov[4];
#pragma unroll
    for (int u = 0; u < 4; u++) {
        unsigned int o = 0;
#pragma unroll
        for (int h = 0; h < 2; h++) {
            int ff = f + 2 * u + h;
            float S = accum[ff], SS = accum[2048 + ff];
            float mean = S * (1.f / 16384.f);
            float var = SS * (1.f / 16384.f) - mean * mean;
            float g = gamma[ff] * rsqrtf(var + 1e-5f);
            float bb = beta[ff] - g * mean;
            float xv = b2f((u16)(wsa[u] >> (16 * h)));
            float v = fmaxf(fmaf(g, xv, bb), 0.f);
            o |= ((unsigned int)f2b(v)) << (16 * h);
        }
        ov[u] = o;
    }
    *(uint4*)(Xp + i) = *(uint4*)ov;
}

// ---------------------- out[b][m][n] fp32 = X1t[b][n][m] + BN3(F2[b][m][n]) ---
__global__ __launch_bounds__(256) void final_tr(const u16* __restrict__ X1t, const u16* __restrict__ F2,
    const float* __restrict__ stats, const float* __restrict__ gamma, const float* __restrict__ beta,
    float* __restrict__ out)
{
    int b = blockIdx.z, mt = blockIdx.y * 64, nt = blockIdx.x * 64;
    __shared__ u16 tl[64][66];
    int t = threadIdx.x, sub = t >> 4, c4 = (t & 15) * 4;
#pragma unroll
    for (int rr = 0; rr < 4; rr++) {
        int row = rr * 16 + sub;  // pixel index within tile
        uint2 v = *(const uint2*)(X1t + ((long)b * 4096 + nt + row) * 1024 + mt + c4);
        *(uint2*)(&tl[row][c4]) = v;
    }
    __syncthreads();
#pragma unroll
    for (int rr = 0; rr < 4; rr++) {
        int row = rr * 16 + sub, m = mt + row;
        float gm = gamma[m] * stats[2 * m + 1];
        float bs = beta[m] - gm * stats[2 * m];
        long gi = ((long)b * 1024 + m) * 4096 + nt + c4;
        uint2 f = *(const uint2*)(F2 + gi);
        float4 o;
        o.x = b2f(tl[c4][row])     + fmaf(gm, b2f((u16)f.x), bs);
        o.y = b2f(tl[c4 + 1][row]) + fmaf(gm, b2f((u16)(f.x >> 16)), bs);
        o.z = b2f(tl[c4 + 2][row]) + fmaf(gm, b2f((u16)f.y), bs);
        o.w = b2f(tl[c4 + 3][row]) + fmaf(gm, b2f((u16)(f.y >> 16)), bs);
        *(float4*)(out + gi) = o;
    }
}

extern "C" void kernel_launch(void* const* d_in, const int* in_sizes, int n_in,
                              void* d_out, int out_size, void* d_ws, size_t ws_size,
                              hipStream_t stream)
{
    const float* x     = (const float*)d_in[0];
    const float* wqkv  = (const float*)d_in[1];
    const float* wproj = (const float*)d_in[2];
    const float* wpe   = (const float*)d_in[3];
    const float* g_n   = (const float*)d_in[4];
    const float* b_n   = (const float*)d_in[5];
    const float* wf1   = (const float*)d_in[6];
    const float* g_f1  = (const float*)d_in[7];
    const float* b_f1  = (const float*)d_in[8];
    const float* wf2   = (const float*)d_in[9];
    const float* g_f2  = (const float*)d_in[10];
    const float* b_f2  = (const float*)d_in[11];
    float* out = (float*)d_out;
    char* ws = (char*)d_ws;

    // workspace layout, total 152,141,824 bytes (~145.1 MiB):
    //   [0, 17.4M)        weights (persistent)
    //   [17.4M, 17.9M)    st1 | accum2+S (zeroed together) | st3
    //   [17.9M, 118.6M)   QKV -> {O2t,X1t}@17.9M + {P,F1p}@51.5M
    //   [118.6M, 152.1M)  Xt -> Oat -> F2
    u16*   Wq      = (u16*)(ws + 0);
    u16*   Wp      = (u16*)(ws + 6291456);
    u16*   W1      = (u16*)(ws + 8388608);
    u16*   W2      = (u16*)(ws + 12582912);
    float* Wpe_eff = (float*)(ws + 16777216);
    float* st1     = (float*)(ws + 17367040);
    float* accum2  = (float*)(ws + 17375232);   // 4096 floats, then S 131072 floats
    float* Sbuf    = (float*)(ws + 17391616);   // 128 x 1024 fp32
    float* st3     = (float*)(ws + 17915904);
    u16*   QKV = (u16*)(ws + 17924096);         // 100.7 MB
    u16*   O2t = (u16*)(ws + 17924096);         // 33.5 MB
    u16*   X1t = (u16*)(ws + 17924096);         // 33.5 MB
    u16*   P   = (u16*)(ws + 51478528);         // 33.5 MB
    u16*   F1p = (u16*)(ws + 51478528);         // 67 MB (pixel-major)
    u16*   Xt  = (u16*)(ws + 118587392);        // 33.5 MB
    u16*   Oat = (u16*)(ws + 118587392);        // 33.5 MB
    u16*   F2  = (u16*)(ws + 118587392);        // 33.5 MB

    zero_f<<<528, 256, 0, stream>>>(accum2);    // accum2 + Sbuf (contiguous)
    build_weights<<<33344, 256, 0, stream>>>(wqkv, wproj, wf1, wf2, wpe, Wq, Wp, W1, W2, Wpe_eff);
    cast_tr<<<dim3(64, 16, 4), 256, 0, stream>>>(x, Xt);
    gemm_bt<false><<<dim3(32, 24, 4), 256, 0, stream>>>(Wq, Xt, QKV, 3072, 4096, 1024, 4096L * 1024, 3072L * 4096);
    attn_s<<<dim3(4, 128), 256, 0, stream>>>(QKV, Sbuf);
    attn_soft<<<128, 64, 0, stream>>>(Sbuf);
    attn_pv<<<dim3(8, 128), 256, 0, stream>>>(QKV, Sbuf, Oat);
    pe_kernel<<<dim3(16, 64, 4), 256, 0, stream>>>(Oat, Wpe_eff, O2t);
    gemm_bt<false><<<dim3(32, 8, 4), 256, 0, stream>>>(Wp, O2t, P, 1024, 4096, 1024, 4096L * 1024, 1024L * 4096);
    bn_stats<<<1024, 256, 0, stream>>>(P, st1, 1024);
    bn_add_tr<<<dim3(64, 16, 4), 256, 0, stream>>>(x, P, st1, g_n, b_n, X1t);
    gemm_bt<true><<<dim3(32, 16, 4), 256, 0, stream>>>(W1, X1t, F1p, 2048, 4096, 1024, 4096L * 1024, 4096L * 2048);
    bn_stats_col<<<128, 256, 0, stream>>>(F1p, accum2);
    bn_relu_ip<<<16384, 256, 0, stream>>>(F1p, accum2, g_f1, b_f1);
    gemm_bt<false><<<dim3(32, 8, 4), 256, 0, stream>>>(W2, F1p, F2, 1024, 4096, 2048, 4096L * 2048, 1024L * 4096);
    bn_stats<<<1024, 256, 0, stream>>>(F2, st3, 1024);
    final_tr<<<dim3(64, 16, 4), 256, 0, stream>>>(X1t, F2, st3, g_f2, b_f2, out);
}

// Round 4
// 780.982 us; speedup vs baseline: 1.2319x; 1.2319x over previous
//
#include <hip/hip_runtime.h>

typedef unsigned short u16;
typedef __bf16 bf16x8 __attribute__((ext_vector_type(8)));
typedef float f32x4 __attribute__((ext_vector_type(4)));

typedef const __attribute__((address_space(1))) void gv_t;
typedef __attribute__((address_space(3))) void lv_t;

__device__ __forceinline__ float b2f(u16 u) {
    union { unsigned int i; float f; } v; v.i = ((unsigned int)u) << 16; return v.f;
}
__device__ __forceinline__ u16 f2b(float f) {
    union { unsigned int i; float f; } v; v.f = f;
    unsigned int b = v.i;
    return (u16)((b + 0x7FFFu + ((b >> 16) & 1u)) >> 16);
}

// Hamilton product tables: out component p, input component q -> weight index / sign
__constant__ int   c_qidx[16] = {0,1,2,3, 1,0,3,2, 2,3,0,1, 3,2,1,0};
__constant__ float c_qsgn[16] = {1,-1,-1,-1, 1,1,1,-1, 1,-1,1,1, 1,1,-1,1};

// ---------------------------------------------------------------- weights ---
// GEMM weights stored in MFMA-fragment order:
//   u16 idx = ((((mtile*KT + ktile)*8 + frag)*4 + quad)*16 + r16)*8 + j
// so a wave's A-fragment read is base + lane*16B, fully coalesced from global.
__device__ __forceinline__ void frag_decode(long i, int KT, int& m, int& k) {
    int j = (int)(i & 7), r16 = (int)((i >> 3) & 15);
    int quad = (int)((i >> 7) & 3), frag = (int)((i >> 9) & 7);
    long t2 = i >> 12;
    int ktile = (int)(t2 % KT), mtile = (int)(t2 / KT);
    m = mtile * 128 + frag * 16 + r16;
    k = ktile * 32 + quad * 8 + j;
}
__device__ __forceinline__ u16 weff(const float* __restrict__ w, int OC, int Cin, int m, int k) {
    int o = m >> 2, p = m & 3, c = k >> 2, q = k & 3, pq = (p << 2) | q;
    return f2b(c_qsgn[pq] * w[c_qidx[pq] * OC + o * Cin + c]);
}

__global__ void build_weights(const float* __restrict__ wqkv, const float* __restrict__ wproj,
                              const float* __restrict__ wf1, const float* __restrict__ wf2,
                              const float* __restrict__ wpe,
                              u16* __restrict__ Wq, u16* __restrict__ Wp, u16* __restrict__ W1,
                              u16* __restrict__ W2, float* __restrict__ Wpe_eff)
{
    long i = (long)blockIdx.x * 256 + threadIdx.x;
    int m, k;
    if (i < 3145728L) {  // qkv: M=3072 K=1024
        frag_decode(i, 32, m, k);
        Wq[i] = weff(wqkv, 196608, 256, m, k);
        return;
    }
    i -= 3145728L;
    if (i < 1048576L) {  // proj: 1024x1024
        frag_decode(i, 32, m, k);
        Wp[i] = weff(wproj, 65536, 256, m, k);
        return;
    }
    i -= 1048576L;
    if (i < 2097152L) {  // f1: 2048x1024
        frag_decode(i, 32, m, k);
        W1[i] = weff(wf1, 131072, 256, m, k);
        return;
    }
    i -= 2097152L;
    if (i < 2097152L) {  // f2: 1024x2048
        frag_decode(i, 64, m, k);
        W2[i] = weff(wf2, 131072, 512, m, k);
        return;
    }
    i -= 2097152L;
    if (i < 147456L) {   // pe: [g][tap][fi][of], fp32
        int g = (int)(i / 2304), r = (int)(i % 2304);
        int tap = r >> 8, r2 = r & 255;
        int fi = r2 >> 4, of = r2 & 15;
        int ol = of >> 2, p = of & 3, ci = fi >> 2, q = fi & 3, pq = (p << 2) | q;
        Wpe_eff[i] = c_qsgn[pq] * wpe[c_qidx[pq] * 9216 + (g * 4 + ol) * 36 + ci * 9 + tap];
    }
}

__global__ void zero_f(float* __restrict__ a)
{
    a[blockIdx.x * 256 + threadIdx.x] = 0.f;
}

// ------------------------------------------------- cast + transpose of x ---
// x fp32 [b][1024][4096] -> Xt bf16 [b][4096][1024]
__global__ __launch_bounds__(256) void cast_tr(const float* __restrict__ x, u16* __restrict__ Xt)
{
    int b = blockIdx.z, mt = blockIdx.y * 64, nt = blockIdx.x * 64;
    __shared__ u16 tl[64][66];
    int t = threadIdx.x, sub = t >> 4, c4 = (t & 15) * 4;
#pragma unroll
    for (int rr = 0; rr < 4; rr++) {
        int row = rr * 16 + sub;
        float4 v = *(const float4*)(x + ((long)b * 1024 + mt + row) * 4096 + nt + c4);
        uint2 pk;
        pk.x = (unsigned int)f2b(v.x) | ((unsigned int)f2b(v.y) << 16);
        pk.y = (unsigned int)f2b(v.z) | ((unsigned int)f2b(v.w) << 16);
        *(uint2*)(&tl[row][c4]) = pk;
    }
    __syncthreads();
#pragma unroll
    for (int rr = 0; rr < 4; rr++) {
        int row = rr * 16 + sub;
        uint2 o;
        o.x = (unsigned int)tl[c4][row] | ((unsigned int)tl[c4 + 1][row] << 16);
        o.y = (unsigned int)tl[c4 + 2][row] | ((unsigned int)tl[c4 + 3][row] << 16);
        *(uint2*)(Xt + ((long)b * 4096 + nt + row) * 1024 + mt + c4) = o;
    }
}

// ------------------------------------------------------------------ GEMM ---
// C = A_frag[M][K] x Bt[b][N][K]^T.  A comes straight from global in MFMA
// fragment order (coalesced 16B/lane, L2-resident, no LDS, no barrier dep).
// B staged via global_load_lds into row-major [128][32] LDS (round-2 pattern).
// TROUT=true writes C[b][N][M] (pixel-major) via LDS epilogue transpose.
__device__ __forceinline__ void async_copy16(const u16* g, u16* l) {
    __builtin_amdgcn_global_load_lds((gv_t*)g, (lv_t*)l, 16, 0, 0);
}

template<bool TROUT>
__global__ __launch_bounds__(256) void gemm_bt(
    const u16* __restrict__ A, const u16* __restrict__ Bt, u16* __restrict__ C,
    int M, int N, int K, long strideB, long strideC)
{
    __shared__ __align__(16) u16 smem[TROUT ? 17408 : 4096];
    u16* Bs = smem;
    const int t = threadIdx.x;
    const int b = blockIdx.z;
    const u16* Bb = Bt + (long)b * strideB;
    const int m0 = blockIdx.y * 128, n0 = blockIdx.x * 128;
    const int l = t & 63, w = t >> 6;
    const int wm = (w >> 1) * 64, wn = (w & 1) * 64;
    const int quad = l >> 4, r16 = l & 15;
    const int row = t >> 2;            // B staging row 0..63
    const int k8 = (t & 3) * 8;        // B staging k offset (8 bf16 = 16B)

    const u16* b_rd = Bs + (wn + r16) * 32 + quad * 8;
    const int KT = K >> 5;
    // A fragment stream: this wave's half (4 frags), lane-contiguous chunks
    const u16* aP = A + (long)blockIdx.y * KT * 4096 + (w >> 1) * 2048 + (long)l * 8;

    f32x4 acc[4][4];
#pragma unroll
    for (int i = 0; i < 4; i++)
#pragma unroll
        for (int j = 0; j < 4; j++) acc[i][j] = (f32x4){0.f, 0.f, 0.f, 0.f};

    const u16* gB0 = Bb + (long)(n0 + row) * K + k8;
    const u16* gB1 = Bb + (long)(n0 + row + 64) * K + k8;
    u16* lB0 = Bs + t * 8; u16* lB1 = Bs + (t + 256) * 8;

    for (int kt = 0; kt < K; kt += 32) {
        async_copy16(gB0 + kt, lB0);
        async_copy16(gB1 + kt, lB1);
        bf16x8 af[4];
#pragma unroll
        for (int i = 0; i < 4; i++) af[i] = *(const bf16x8*)(aP + i * 512);
        aP += 4096;
        __syncthreads();
        bf16x8 bfr[4];
#pragma unroll
        for (int j = 0; j < 4; j++) bfr[j] = *(const bf16x8*)(b_rd + j * 512);
#pragma unroll
        for (int i = 0; i < 4; i++)
#pragma unroll
            for (int j = 0; j < 4; j++)
                acc[i][j] = __builtin_amdgcn_mfma_f32_16x16x32_bf16(af[i], bfr[j], acc[i][j], 0, 0, 0);
        __syncthreads();
    }

    if (!TROUT) {
        u16* Cb = C + (long)b * strideC;
#pragma unroll
        for (int i = 0; i < 4; i++)
#pragma unroll
            for (int j = 0; j < 4; j++) {
                int mm = m0 + wm + i * 16 + quad * 4;
                int nn = n0 + wn + j * 16 + r16;
#pragma unroll
                for (int r = 0; r < 4; r++)
                    Cb[(long)(mm + r) * N + nn] = f2b(acc[i][j][r]);
            }
    } else {
        u16* Ct = smem;
#pragma unroll
        for (int i = 0; i < 4; i++)
#pragma unroll
            for (int j = 0; j < 4; j++) {
                int mm = wm + i * 16 + quad * 4;
                int nn = wn + j * 16 + r16;
                ushort4 pk;
                pk.x = f2b(acc[i][j][0]); pk.y = f2b(acc[i][j][1]);
                pk.z = f2b(acc[i][j][2]); pk.w = f2b(acc[i][j][3]);
                *(ushort4*)(Ct + nn * 136 + mm) = pk;
            }
        __syncthreads();
        u16* Cb = C + (long)b * strideC;
        for (int rr = 0; rr < 128; rr += 16) {
            int n = rr + (t >> 4);
            int m8 = (t & 15) * 8;
            uint4 v = *(const uint4*)(Ct + n * 136 + m8);
            *(uint4*)(Cb + (long)(n0 + n) * M + m0 + m8) = v;
        }
    }
}

// ------------------------------------------------------------- attention ---
// Phase 1: partial S over 1024-pixel chunks, 512 blocks, atomicAdd reduce.
__global__ __launch_bounds__(256) void attn_s(const u16* __restrict__ QKV, float* __restrict__ S)
{
    const int chunk = blockIdx.x, bhp = blockIdx.y;
    const int bi = bhp >> 5, h = (bhp >> 2) & 7, p = bhp & 3;
    const long rs = 16384;
    const u16* base = QKV + (long)bi * (3072L * 4096) + (long)(h * 384 + p) * 4096;
    const int t = threadIdx.x, l = t & 63, w = t >> 6;
    const int quad = l >> 4, r16 = l & 15;
    __shared__ float Sred[4][32][32];

    f32x4 acc[2][2];
#pragma unroll
    for (int i = 0; i < 2; i++)
#pragma unroll
        for (int j = 0; j < 2; j++) acc[i][j] = (f32x4){0.f, 0.f, 0.f, 0.f};

    const int nb = chunk * 1024 + w * 256 + quad * 8;
    for (int kk = 0; kk < 256; kk += 32) {
        long off = nb + kk;
        bf16x8 q0 = *(const bf16x8*)(base + (long)r16 * rs + off);
        bf16x8 q1 = *(const bf16x8*)(base + (long)(16 + r16) * rs + off);
        bf16x8 k0 = *(const bf16x8*)(base + (long)(32 + r16) * rs + off);
        bf16x8 k1 = *(const bf16x8*)(base + (long)(48 + r16) * rs + off);
        acc[0][0] = __builtin_amdgcn_mfma_f32_16x16x32_bf16(q0, k0, acc[0][0], 0, 0, 0);
        acc[0][1] = __builtin_amdgcn_mfma_f32_16x16x32_bf16(q0, k1, acc[0][1], 0, 0, 0);
        acc[1][0] = __builtin_amdgcn_mfma_f32_16x16x32_bf16(q1, k0, acc[1][0], 0, 0, 0);
        acc[1][1] = __builtin_amdgcn_mfma_f32_16x16x32_bf16(q1, k1, acc[1][1], 0, 0, 0);
    }
#pragma unroll
    for (int i = 0; i < 2; i++)
#pragma unroll
        for (int j = 0; j < 2; j++)
#pragma unroll
            for (int r = 0; r < 4; r++)
                Sred[w][i * 16 + quad * 4 + r][j * 16 + r16] = acc[i][j][r];
    __syncthreads();
    for (int e = t; e < 1024; e += 256) {
        int c = e >> 5, d = e & 31;
        float v = Sred[0][c][d] + Sred[1][c][d] + Sred[2][c][d] + Sred[3][c][d];
        atomicAdd(&S[(long)bhp * 1024 + e], v);
    }
}

// Phase 2: scale + softmax rows, in place.  128 tiny blocks.
__global__ __launch_bounds__(64) void attn_soft(float* __restrict__ S)
{
    const int bhp = blockIdx.x, t = threadIdx.x;
    if (t >= 32) return;
    float* row = S + (long)bhp * 1024 + t * 32;
    float r[32];
    float mx = -1e30f;
#pragma unroll
    for (int d = 0; d < 32; d++) { r[d] = row[d] * 0.17677669529663687f; mx = fmaxf(mx, r[d]); }
    float sum = 0.f;
#pragma unroll
    for (int d = 0; d < 32; d++) { r[d] = __expf(r[d] - mx); sum += r[d]; }
    float inv = 1.f / sum;
#pragma unroll
    for (int d = 0; d < 32; d++) row[d] = r[d] * inv;
}

// Phase 3: O = P V.  1024 blocks, 512 pixels each, 2 px/thread.
__global__ __launch_bounds__(256) void attn_pv(const u16* __restrict__ QKV, const float* __restrict__ S,
                                               u16* __restrict__ O)
{
    const int ns = blockIdx.x * 512, bhp = blockIdx.y;
    const int bi = bhp >> 5, h = (bhp >> 2) & 7, p = bhp & 3;
    const long rs = 16384;
    const u16* base = QKV + (long)bi * (3072L * 4096) + (long)(h * 384 + p) * 4096;
    const int t = threadIdx.x;
    __shared__ float Pl[1024];
    for (int e = t; e < 1024; e += 256) Pl[e] = S[(long)bhp * 1024 + e];
    __syncthreads();

    float v[32][2];
#pragma unroll
    for (int d = 0; d < 32; d++) {
        unsigned int u = *(const unsigned int*)(base + (long)(64 + d) * rs + ns + 2 * t);
        v[d][0] = b2f((u16)u); v[d][1] = b2f((u16)(u >> 16));
    }
    u16* Ob = O + (long)bi * (1024L * 4096) + (long)(h * 128 + p) * 4096;
    for (int c = 0; c < 32; c++) {
        float s0 = 0.f, s1 = 0.f;
        const float4* prow = (const float4*)(&Pl[c * 32]);
#pragma unroll
        for (int dq = 0; dq < 8; dq++) {
            float4 pv = prow[dq];
            s0 = fmaf(pv.x, v[4*dq+0][0], s0); s1 = fmaf(pv.x, v[4*dq+0][1], s1);
            s0 = fmaf(pv.y, v[4*dq+1][0], s0); s1 = fmaf(pv.y, v[4*dq+1][1], s1);
            s0 = fmaf(pv.z, v[4*dq+2][0], s0); s1 = fmaf(pv.z, v[4*dq+2][1], s1);
            s0 = fmaf(pv.w, v[4*dq+3][0], s0); s1 = fmaf(pv.w, v[4*dq+3][1], s1);
        }
        *(unsigned int*)(Ob + (long)c * 16384 + ns + 2 * t) =
            (unsigned int)f2b(s0) | ((unsigned int)f2b(s1) << 16);
    }
}

// ------------------------------------------------------ pe conv + residual ---
// O2t[b][n][feat] = O + qconv_pe(O)
__global__ __launch_bounds__(256) void pe_kernel(const u16* __restrict__ Oin,
                                                 const float* __restrict__ Wpe,
                                                 u16* __restrict__ O2t)
{
    const int tile = blockIdx.x, g = blockIdx.y, bi = blockIdx.z;
    const int y0 = (tile >> 2) * 16, x0 = (tile & 3) * 16;
    __shared__ float tin[16][324];  // 16 feats x 18x18 halo tile
    const int t = threadIdx.x;
    const u16* Ob = Oin + (long)bi * (1024L * 4096) + (long)(g * 16) * 4096;
    for (int e = t; e < 16 * 324; e += 256) {
        int f = e / 324, rem = e % 324;
        int yy = rem / 18 - 1 + y0, xx = rem % 18 - 1 + x0;
        float v = 0.f;
        if (yy >= 0 && yy < 64 && xx >= 0 && xx < 64)
            v = b2f(Ob[(long)f * 4096 + yy * 64 + xx]);
        tin[f][rem] = v;
    }
    __syncthreads();
    const int y = t >> 4, x = t & 15;
    float acc[16];
#pragma unroll
    for (int of = 0; of < 16; of++) acc[of] = tin[of][(y + 1) * 18 + (x + 1)];  // residual
    const float* Wg = Wpe + g * 2304;
    for (int dy = 0; dy < 3; dy++)
        for (int dx = 0; dx < 3; dx++) {
            int off = (y + dy) * 18 + (x + dx);
            int tap = dy * 3 + dx;
            for (int fi = 0; fi < 16; fi++) {
                float v = tin[fi][off];
                const float* wp = Wg + (tap * 16 + fi) * 16;
#pragma unroll
                for (int of = 0; of < 16; of++) acc[of] = fmaf(wp[of], v, acc[of]);
            }
        }
    long n = (long)(y0 + y) * 64 + (x0 + x);
    unsigned int* op = (unsigned int*)(O2t + ((long)bi * 4096 + n) * 1024 + g * 16);
#pragma unroll
    for (int u = 0; u < 8; u++)
        op[u] = (unsigned int)f2b(acc[2 * u]) | ((unsigned int)f2b(acc[2 * u + 1]) << 16);
}

// ----------------------------------------- BN stats, feature-major layout ---
__global__ __launch_bounds__(256) void bn_stats(const u16* __restrict__ X, float* __restrict__ stats, int M)
{
    const int m = blockIdx.x, t = threadIdx.x;
    float s = 0.f, ss = 0.f;
    for (int b = 0; b < 4; b++) {
        const u16* rowp = X + ((long)b * M + m) * 4096;
        for (int pass = 0; pass < 2; pass++) {
            uint4 uv = *(const uint4*)(rowp + pass * 2048 + t * 8);
            unsigned int wsa[4] = {uv.x, uv.y, uv.z, uv.w};
#pragma unroll
            for (int u = 0; u < 4; u++) {
                float v0 = b2f((u16)wsa[u]), v1 = b2f((u16)(wsa[u] >> 16));
                s += v0 + v1; ss += v0 * v0 + v1 * v1;
            }
        }
    }
    __shared__ float rs[4], rss[4];
    for (int o = 32; o > 0; o >>= 1) { s += __shfl_down(s, o); ss += __shfl_down(ss, o); }
    if ((t & 63) == 0) { rs[t >> 6] = s; rss[t >> 6] = ss; }
    __syncthreads();
    if (t == 0) {
        float S = rs[0] + rs[1] + rs[2] + rs[3];
        float SS = rss[0] + rss[1] + rss[2] + rss[3];
        float mean = S * (1.f / 16384.f);
        float var = SS * (1.f / 16384.f) - mean * mean;
        stats[2 * m] = mean;
        stats[2 * m + 1] = rsqrtf(var + 1e-5f);
    }
}

// ------------------------------------------- X1t = cast_tr(x + BN(P)) bf16 ---
__global__ __launch_bounds__(256) void bn_add_tr(const float* __restrict__ x, const u16* __restrict__ P,
    const float* __restrict__ stats, const float* __restrict__ gamma, const float* __restrict__ beta,
    u16* __restrict__ X1t)
{
    int b = blockIdx.z, mt = blockIdx.y * 64, nt = blockIdx.x * 64;
    __shared__ u16 tl[64][66];
    int t = threadIdx.x, sub = t >> 4, c4 = (t & 15) * 4;
#pragma unroll
    for (int rr = 0; rr < 4; rr++) {
        int row = rr * 16 + sub, m = mt + row;
        float gm = gamma[m] * stats[2 * m + 1];
        float bs = beta[m] - gm * stats[2 * m];
        long gi = ((long)b * 1024 + m) * 4096 + nt + c4;
        float4 xv = *(const float4*)(x + gi);
        uint2 pv = *(const uint2*)(P + gi);
        uint2 pk;
        pk.x = (unsigned int)f2b(xv.x + fmaf(gm, b2f((u16)pv.x), bs)) |
               ((unsigned int)f2b(xv.y + fmaf(gm, b2f((u16)(pv.x >> 16)), bs)) << 16);
        pk.y = (unsigned int)f2b(xv.z + fmaf(gm, b2f((u16)pv.y), bs)) |
               ((unsigned int)f2b(xv.w + fmaf(gm, b2f((u16)(pv.y >> 16)), bs)) << 16);
        *(uint2*)(&tl[row][c4]) = pk;
    }
    __syncthreads();
#pragma unroll
    for (int rr = 0; rr < 4; rr++) {
        int row = rr * 16 + sub;
        uint2 o;
        o.x = (unsigned int)tl[c4][row] | ((unsigned int)tl[c4 + 1][row] << 16);
        o.y = (unsigned int)tl[c4 + 2][row] | ((unsigned int)tl[c4 + 3][row] << 16);
        *(uint2*)(X1t + ((long)b * 4096 + nt + row) * 1024 + mt + c4) = o;
    }
}

// ----------------------------- BN stats over pixel-major [16384][2048] bf16 ---
__global__ __launch_bounds__(256) void bn_stats_col(const u16* __restrict__ Xp, float* __restrict__ accum)
{
    const int t = threadIdx.x;
    const int f0 = t * 8;
    float s[8], ss[8];
#pragma unroll
    for (int u = 0; u < 8; u++) { s[u] = 0.f; ss[u] = 0.f; }
    const u16* base = Xp + (long)blockIdx.x * 128 * 2048;
    for (int r = 0; r < 128; r++) {
        uint4 uv = *(const uint4*)(base + (long)r * 2048 + f0);
        unsigned int wsa[4] = {uv.x, uv.y, uv.z, uv.w};
#pragma unroll
        for (int u = 0; u < 4; u++) {
            float v0 = b2f((u16)wsa[u]), v1 = b2f((u16)(wsa[u] >> 16));
            s[2*u] += v0;   ss[2*u]   += v0 * v0;
            s[2*u+1] += v1; ss[2*u+1] += v1 * v1;
        }
    }
#pragma unroll
    for (int u = 0; u < 8; u++) {
        atomicAdd(&accum[f0 + u], s[u]);
        atomicAdd(&accum[2048 + f0 + u], ss[u]);
    }
}

// --------------------------------- in-place relu(BN(.)) on pixel-major F1 ---
__global__ __launch_bounds__(256) void bn_relu_ip(u16* __restrict__ Xp, const float* __restrict__ accum,
    const float* __restrict__ gamma, const float* __restrict__ beta)
{
    long i = ((long)blockIdx.x * 256 + threadIdx.x) * 8;
    int f = (int)(i & 2047);
    uint4 uv = *(const uint4*)(Xp + i);
    unsigned int wsa[4] = {uv.x, uv.y, uv.z, uv.w};
    unsigned int ov[4];
#pragma unroll
    for (int u = 0; u < 4; u++) {
        unsigned int o = 0;
#pragma unroll
        for (int h = 0; h < 2; h++) {
            int ff = f + 2 * u + h;
            float S = accum[ff], SS = accum[2048 + ff];
            float mean = S * (1.f / 16384.f);
            float var = SS * (1.f / 16384.f) - mean * mean;
            float g = gamma[ff] * rsqrtf(var + 1e-5f);
            float bb = beta[ff] - g * mean;
            float xv = b2f((u16)(wsa[u] >> (16 * h)));
            float v = fmaxf(fmaf(g, xv, bb), 0.f);
            o |= ((unsigned int)f2b(v)) << (16 * h);
        }
        ov[u] = o;
    }
    *(uint4*)(Xp + i) = *(uint4*)ov;
}

// ---------------------- out[b][m][n] fp32 = X1t[b][n][m] + BN3(F2[b][m][n]) ---
__global__ __launch_bounds__(256) void final_tr(const u16* __restrict__ X1t, const u16* __restrict__ F2,
    const float* __restrict__ stats, const float* __restrict__ gamma, const float* __restrict__ beta,
    float* __restrict__ out)
{
    int b = blockIdx.z, mt = blockIdx.y * 64, nt = blockIdx.x * 64;
    __shared__ u16 tl[64][66];
    int t = threadIdx.x, sub = t >> 4, c4 = (t & 15) * 4;
#pragma unroll
    for (int rr = 0; rr < 4; rr++) {
        int row = rr * 16 + sub;  // pixel index within tile
        uint2 v = *(const uint2*)(X1t + ((long)b * 4096 + nt + row) * 1024 + mt + c4);
        *(uint2*)(&tl[row][c4]) = v;
    }
    __syncthreads();
#pragma unroll
    for (int rr = 0; rr < 4; rr++) {
        int row = rr * 16 + sub, m = mt + row;
        float gm = gamma[m] * stats[2 * m + 1];
        float bs = beta[m] - gm * stats[2 * m];
        long gi = ((long)b * 1024 + m) * 4096 + nt + c4;
        uint2 f = *(const uint2*)(F2 + gi);
        float4 o;
        o.x = b2f(tl[c4][row])     + fmaf(gm, b2f((u16)f.x), bs);
        o.y = b2f(tl[c4 + 1][row]) + fmaf(gm, b2f((u16)(f.x >> 16)), bs);
        o.z = b2f(tl[c4 + 2][row]) + fmaf(gm, b2f((u16)f.y), bs);
        o.w = b2f(tl[c4 + 3][row]) + fmaf(gm, b2f((u16)(f.y >> 16)), bs);
        *(float4*)(out + gi) = o;
    }
}

extern "C" void kernel_launch(void* const* d_in, const int* in_sizes, int n_in,
                              void* d_out, int out_size, void* d_ws, size_t ws_size,
                              hipStream_t stream)
{
    const float* x     = (const float*)d_in[0];
    const float* wqkv  = (const float*)d_in[1];
    const float* wproj = (const float*)d_in[2];
    const float* wpe   = (const float*)d_in[3];
    const float* g_n   = (const float*)d_in[4];
    const float* b_n   = (const float*)d_in[5];
    const float* wf1   = (const float*)d_in[6];
    const float* g_f1  = (const float*)d_in[7];
    const float* b_f1  = (const float*)d_in[8];
    const float* wf2   = (const float*)d_in[9];
    const float* g_f2  = (const float*)d_in[10];
    const float* b_f2  = (const float*)d_in[11];
    float* out = (float*)d_out;
    char* ws = (char*)d_ws;

    // workspace layout, total 152,141,824 bytes (~145.1 MiB):
    //   [0, 17.4M)        weights (persistent)
    //   [17.4M, 17.9M)    st1 | accum2+S (zeroed together) | st3
    //   [17.9M, 118.6M)   QKV -> {O2t,X1t}@17.9M + {P,F1p}@51.5M
    //   [118.6M, 152.1M)  Xt -> Oat -> F2
    u16*   Wq      = (u16*)(ws + 0);
    u16*   Wp      = (u16*)(ws + 6291456);
    u16*   W1      = (u16*)(ws + 8388608);
    u16*   W2      = (u16*)(ws + 12582912);
    float* Wpe_eff = (float*)(ws + 16777216);
    float* st1     = (float*)(ws + 17367040);
    float* accum2  = (float*)(ws + 17375232);   // 4096 floats, then S 131072 floats
    float* Sbuf    = (float*)(ws + 17391616);   // 128 x 1024 fp32
    float* st3     = (float*)(ws + 17915904);
    u16*   QKV = (u16*)(ws + 17924096);         // 100.7 MB
    u16*   O2t = (u16*)(ws + 17924096);         // 33.5 MB
    u16*   X1t = (u16*)(ws + 17924096);         // 33.5 MB
    u16*   P   = (u16*)(ws + 51478528);         // 33.5 MB
    u16*   F1p = (u16*)(ws + 51478528);         // 67 MB (pixel-major)
    u16*   Xt  = (u16*)(ws + 118587392);        // 33.5 MB
    u16*   Oat = (u16*)(ws + 118587392);        // 33.5 MB
    u16*   F2  = (u16*)(ws + 118587392);        // 33.5 MB

    zero_f<<<528, 256, 0, stream>>>(accum2);    // accum2 + Sbuf (contiguous)
    build_weights<<<33344, 256, 0, stream>>>(wqkv, wproj, wf1, wf2, wpe, Wq, Wp, W1, W2, Wpe_eff);
    cast_tr<<<dim3(64, 16, 4), 256, 0, stream>>>(x, Xt);
    gemm_bt<false><<<dim3(32, 24, 4), 256, 0, stream>>>(Wq, Xt, QKV, 3072, 4096, 1024, 4096L * 1024, 3072L * 4096);
    attn_s<<<dim3(4, 128), 256, 0, stream>>>(QKV, Sbuf);
    attn_soft<<<128, 64, 0, stream>>>(Sbuf);
    attn_pv<<<dim3(8, 128), 256, 0, stream>>>(QKV, Sbuf, Oat);
    pe_kernel<<<dim3(16, 64, 4), 256, 0, stream>>>(Oat, Wpe_eff, O2t);
    gemm_bt<false><<<dim3(32, 8, 4), 256, 0, stream>>>(Wp, O2t, P, 1024, 4096, 1024, 4096L * 1024, 1024L * 4096);
    bn_stats<<<1024, 256, 0, stream>>>(P, st1, 1024);
    bn_add_tr<<<dim3(64, 16, 4), 256, 0, stream>>>(x, P, st1, g_n, b_n, X1t);
    gemm_bt<true><<<dim3(32, 16, 4), 256, 0, stream>>>(W1, X1t, F1p, 2048, 4096, 1024, 4096L * 1024, 4096L * 2048);
    bn_stats_col<<<128, 256, 0, stream>>>(F1p, accum2);
    bn_relu_ip<<<16384, 256, 0, stream>>>(F1p, accum2, g_f1, b_f1);
    gemm_bt<false><<<dim3(32, 8, 4), 256, 0, stream>>>(W2, F1p, F2, 1024, 4096, 2048, 4096L * 2048, 1024L * 4096);
    bn_stats<<<1024, 256, 0, stream>>>(F2, st3, 1024);
    final_tr<<<dim3(64, 16, 4), 256, 0, stream>>>(X1t, F2, st3, g_f2, b_f2, out);
}